// Round 7
// baseline (160.244 us; speedup 1.0000x reference)
//
#include <hip/hip_runtime.h>
#include <hip/hip_bf16.h>

#define BATCH 32
#define DIM   128
#define NPTS  2048
#define NCH   16          // 16-byte chunks (8 bf16) per point
#define BIGF  1e30f

// ws byte offsets; images are CHUNK-MAJOR: img[b][c][n] in 16B units
#define OFF_XT    0ull
#define OFF_YT    16777216ull
#define OFF_XN    33554432ull
#define OFF_YN    (OFF_XN + 262144ull)
#define OFF_RMIN  (OFF_XN + 2ull * 262144ull)
#define OFF_CMIN  (OFF_XN + 3ull * 262144ull)
#define OFF_LEN   (OFF_XN + 4ull * 262144ull)   // 32 ints
#define OFF_ITEMS (OFF_LEN + 128ull)            // up to 512 ints
#define OFF_CTR   (OFF_ITEMS + 2048ull)         // 1 int
#define OFF_NIT   (OFF_CTR + 4ull)              // 1 int

typedef __bf16 bf16x8 __attribute__((ext_vector_type(8)));
typedef float  f32x16 __attribute__((ext_vector_type(16)));
typedef unsigned int u32;

#define ZERO16 {0.f,0.f,0.f,0.f,0.f,0.f,0.f,0.f,0.f,0.f,0.f,0.f,0.f,0.f,0.f,0.f}

__device__ __forceinline__ bool mask_is_i32(const void* m) {
  // mask[0][1] is guaranteed true (lens >= N/2 > 1); for int32 its byte 1 is 0.
  return ((const unsigned char*)m)[1] == 0;
}
__device__ __forceinline__ bool mask_at(const void* m, bool i32, int idx) {
  return i32 ? (((const int*)m)[idx] != 0) : (((const unsigned char*)m)[idx] != 0);
}

// async 16B global -> LDS (dst must be wave-linear: base + lane*16)
__device__ __forceinline__ void gll16(const void* g, void* l) {
  __builtin_amdgcn_global_load_lds(
      (const __attribute__((address_space(1))) u32*)g,
      (__attribute__((address_space(3))) u32*)l, 16, 0, 0);
}

// -------- kernel 0: lens (binary search on prefix mask) + work items + ctr --------
__global__ void chamfer_items(const void* __restrict__ mask, char* __restrict__ ws) {
  __shared__ int cnts[32], offs[32];
  int tid = threadIdx.x;          // 64 threads
  bool i32m = mask_is_i32(mask);
  if (tid < 32) {
    int lo = 0, hi = NPTS;
    while (lo < hi) {             // prefix mask: len = first false index
      int mid = (lo + hi) >> 1;
      if (mask_at(mask, i32m, tid * NPTS + mid)) lo = mid + 1; else hi = mid;
    }
    ((int*)(ws + OFF_LEN))[tid] = lo;
    cnts[tid] = (lo + 127) >> 7;  // 128-row i-tiles
  }
  __syncthreads();
  if (tid == 0) {
    int acc = 0;
    for (int b = 0; b < 32; ++b) { offs[b] = acc; acc += cnts[b]; }
    ((int*)(ws + OFF_NIT))[0] = acc;
    ((int*)(ws + OFF_CTR))[0] = 0;
  }
  __syncthreads();
  if (tid < 32) {
    int o = offs[tid], c = cnts[tid];
    int* items = (int*)(ws + OFF_ITEMS);
    for (int k = 0; k < c; ++k) items[o + k] = (tid << 8) | k;
  }
}

// -------- kernel 1: coalesced transpose -> chunk-major bf16 image + norms --------
// grid: 2 arr x 32 b x 32 nt = 2048 blocks, 256 threads; tile 128 d x 64 n
__global__ void chamfer_prep(const float* __restrict__ x, const float* __restrict__ y,
                             const void* __restrict__ mask, char* __restrict__ ws,
                             float* __restrict__ out) {
  __shared__ float buf[128 * 65];       // [d][n], pitch 65 words -> 2-way banks
  __shared__ float nrm_part[4][64];

  int blk = blockIdx.x;
  int arr = blk >> 10;
  int b   = (blk >> 5) & 31;
  int nt  = blk & 31;
  int n0  = nt << 6;                    // 64 points per block
  int tid = threadIdx.x;
  bool i32m = mask_is_i32(mask);

  if (blk == 0 && tid == 0) out[0] = 0.f;

  float*    nrm  = (float*)(ws + (arr ? OFF_YN : OFF_XN));
  unsigned* cmin = (unsigned*)(ws + OFF_CMIN);

  // prefix mask: tile fully invalid iff its first point is invalid
  if (!mask_at(mask, i32m, b * NPTS + n0)) {
    if (tid < 64) {
      nrm[b * NPTS + n0 + tid] = BIGF;
      if (arr) cmin[b * NPTS + n0 + tid] = __float_as_uint(BIGF);
    }
    return;
  }

  const float* src = (arr ? y : x) + (size_t)b * DIM * NPTS;
#pragma unroll
  for (int k = 0; k < 8; ++k) {
    int idx = k * 256 + tid;            // 128 d x 16 float4-cols
    int d = idx >> 4, c4 = idx & 15;
    *(float4*)&buf[d * 65 + c4 * 4] =
        *(const float4*)(src + (size_t)d * NPTS + n0 + c4 * 4);
  }
  __syncthreads();

  int n = tid & 63, grp = tid >> 6;     // grp: 32 dims each
  char* imgbase = ws + (arr ? OFF_YT : OFF_XT);
  float sq = 0.f;
#pragma unroll
  for (int cl = 0; cl < 4; ++cl) {
    unsigned short h[8];
#pragma unroll
    for (int q = 0; q < 8; ++q) {
      float v = buf[(grp * 32 + cl * 8 + q) * 65 + n];
      __hip_bfloat16 bv = __float2bfloat16(v);
      h[q] = *(unsigned short*)&bv;
      float vb = __bfloat162float(bv);
      sq = fmaf(vb, vb, sq);            // norm from ROUNDED value (matches MFMA)
    }
    uint4 pk;
    pk.x = h[0] | ((unsigned)h[1] << 16);
    pk.y = h[2] | ((unsigned)h[3] << 16);
    pk.z = h[4] | ((unsigned)h[5] << 16);
    pk.w = h[6] | ((unsigned)h[7] << 16);
    int cg = grp * 4 + cl;
    // chunk-major: consecutive n lanes -> contiguous 1KB writes
    *(uint4*)(imgbase + (((size_t)(b * NCH + cg) * NPTS + n0 + n) << 4)) = pk;
  }
  nrm_part[grp][n] = sq;
  __syncthreads();
  if (grp == 0) {
    float tot = nrm_part[0][n] + nrm_part[1][n] + nrm_part[2][n] + nrm_part[3][n];
    int row = n0 + n;
    bool valid = mask_at(mask, i32m, b * NPTS + row);
    nrm[b * NPTS + row] = valid ? tot : BIGF;
    if (arr) cmin[b * NPTS + row] = __float_as_uint(BIGF);
  }
}

// -------- kernel 2: MFMA distance + mins (persistent blocks + work queue) --------
__global__ __launch_bounds__(512, 4)
void chamfer_dist(char* __restrict__ ws) {
  __shared__ __align__(16) char ysl[2][NCH * 128 * 16];  // 2 x 32 KB, chunk-major
  __shared__ unsigned colmin_lds[NPTS];                  // 8 KB
  __shared__ unsigned rowmin_lds[128];
  __shared__ int sh_item;

  int tid = threadIdx.x, lane = tid & 63, w = tid >> 6;
  int qrow = w >> 1, qcol = w & 1;      // wave: 32 rows x 64 cols
  int la31 = lane & 31, la5 = lane >> 5;

  int* ctr = (int*)(ws + OFF_CTR);
  const int* items = (const int*)(ws + OFF_ITEMS);
  const int* leng  = (const int*)(ws + OFF_LEN);
  int n_items = *(const int*)(ws + OFF_NIT);

  for (;;) {
    if (tid == 0) sh_item = atomicAdd(ctr, 1);
    __syncthreads();
    int ii = sh_item;
    if (ii >= n_items) break;
    int itm = items[ii];
    int b = itm >> 8, i0 = (itm & 255) << 7;
    int len = leng[b];
    int nT = (len + 127) >> 7;          // 128-col j-tiles
    int jmax = nT << 7;

    const char* xTb = ws + OFF_XT + ((size_t)b * NCH * NPTS << 4);
    const char* yTb = ws + OFF_YT + ((size_t)b * NCH * NPTS << 4);
    const float* xng = (const float*)(ws + OFF_XN) + b * NPTS;
    const float* yng = (const float*)(ws + OFF_YN) + b * NPTS;
    float*    rowming = (float*)(ws + OFF_RMIN) + b * NPTS;
    unsigned* colming = (unsigned*)(ws + OFF_CMIN) + b * NPTS;

    for (int idx = tid; idx < jmax; idx += 512)
      colmin_lds[idx] = __float_as_uint(BIGF);
    if (tid < 128) rowmin_lds[tid] = __float_as_uint(BIGF);

    // A fragments -> registers (coalesced chunk-major reads, reused all jt)
    int r0 = i0 + qrow * 32 + la31;
    bf16x8 Areg[8];
#pragma unroll
    for (int kc = 0; kc < 8; ++kc)
      Areg[kc] = *(const bf16x8*)(xTb + (((size_t)(kc * 2 + la5) * NPTS + r0) << 4));

    // xn for this wave's rows (C/D layout: row=(r&3)+8*(r>>2)+4*la5)
    float xnr[16], rmin[16];
#pragma unroll
    for (int r = 0; r < 16; ++r) {
      int row_l = (r & 3) + ((r >> 2) << 3) + (la5 << 2);
      xnr[r] = xng[i0 + qrow * 32 + row_l];
      rmin[r] = BIGF;                   // tracks min_j(yn_j - 2*dot)
    }

    // stage tile 0 (async global->LDS, wave-linear dst)
#pragma unroll
    for (int k = 0; k < 4; ++k) {
      int idx = k * 512 + tid;          // c = idx>>7, jl = idx&127
      gll16(yTb + (((size_t)(idx >> 7) * NPTS + (idx & 127)) << 4),
            ysl[0] + idx * 16);
    }
    __syncthreads();

    for (int jt = 0; jt < nT; ++jt) {
      int cur = jt & 1;
      if (jt + 1 < nT) {                // prefetch next tile before compute
        int j0n = (jt + 1) << 7;
#pragma unroll
        for (int k = 0; k < 4; ++k) {
          int idx = k * 512 + tid;
          gll16(yTb + (((size_t)(idx >> 7) * NPTS + j0n + (idx & 127)) << 4),
                ysl[cur ^ 1] + idx * 16);
        }
      }
      int j0t = (jt << 7) + qcol * 64;
      float ynr0 = yng[j0t + la31];
      float ynr1 = yng[j0t + 32 + la31];

      const char* ybuf = ysl[cur];
      f32x16 acc0 = ZERO16, acc1 = ZERO16;
#pragma unroll
      for (int kc = 0; kc < 8; ++kc) {
        int boff = ((kc * 2 + la5) * 128 + qcol * 64 + la31) << 4;
        bf16x8 b0 = *(const bf16x8*)(ybuf + boff);
        bf16x8 b1 = *(const bf16x8*)(ybuf + boff + (32 << 4));
        acc0 = __builtin_amdgcn_mfma_f32_32x32x16_bf16(Areg[kc], b0, acc0, 0, 0, 0);
        acc1 = __builtin_amdgcn_mfma_f32_32x32x16_bf16(Areg[kc], b1, acc1, 0, 0, 0);
      }
      float cm0 = BIGF, cm1 = BIGF;
#pragma unroll
      for (int r = 0; r < 16; ++r) {
        float u0 = fmaf(-2.f, acc0[r], ynr0);
        float u1 = fmaf(-2.f, acc1[r], ynr1);
        rmin[r] = fminf(rmin[r], fminf(u0, u1));
        cm0 = fminf(cm0, u0 + xnr[r]);
        cm1 = fminf(cm1, u1 + xnr[r]);
      }
      cm0 = fminf(cm0, __shfl_xor(cm0, 32));   // la5 halves hold different rows
      cm1 = fminf(cm1, __shfl_xor(cm1, 32));
      if (lane < 32) {
        atomicMin(&colmin_lds[j0t + la31],      __float_as_uint(fmaxf(cm0, 0.f)));
        atomicMin(&colmin_lds[j0t + 32 + la31], __float_as_uint(fmaxf(cm1, 0.f)));
      }
      __syncthreads();                  // drains prefetch (vmcnt 0) + ybuf reuse
    }

    // rowmin: reduce across 32 j-lanes, then merge qcol halves via LDS atomics
#pragma unroll
    for (int r = 0; r < 16; ++r) {
      float v = rmin[r];
      v = fminf(v, __shfl_xor(v, 1));
      v = fminf(v, __shfl_xor(v, 2));
      v = fminf(v, __shfl_xor(v, 4));
      v = fminf(v, __shfl_xor(v, 8));
      v = fminf(v, __shfl_xor(v, 16));
      if (la31 == 0) {
        int row_l = qrow * 32 + (r & 3) + ((r >> 2) << 3) + (la5 << 2);
        atomicMin(&rowmin_lds[row_l], __float_as_uint(fmaxf(v + xnr[r], 0.f)));
      }
    }
    __syncthreads();
    if (tid < 128) rowming[i0 + tid] = __uint_as_float(rowmin_lds[tid]);
    for (int idx = tid; idx < jmax; idx += 512)
      atomicMin(&colming[idx], colmin_lds[idx]);
    __syncthreads();                    // colmin_lds/rowmin_lds reuse next item
  }
}

// ---------------- kernel 3: masked sums + mean ----------------
__global__ void chamfer_reduce(const char* __restrict__ ws, const void* __restrict__ mask,
                               float* __restrict__ out) {
  __shared__ float red[256];
  int blk = blockIdx.x;
  int b = blk >> 2, sl = blk & 3;
  int tid = threadIdx.x;
  bool i32m = mask_is_i32(mask);
  const float*    rowmin = (const float*)(ws + OFF_RMIN) + b * NPTS;
  const unsigned* colmin = (const unsigned*)(ws + OFF_CMIN) + b * NPTS;
  float s = 0.f;
#pragma unroll
  for (int k = 0; k < 2; ++k) {
    int i = sl * 512 + k * 256 + tid;
    if (mask_at(mask, i32m, b * NPTS + i))
      s += rowmin[i] + __uint_as_float(colmin[i]);
  }
  red[tid] = s;
  __syncthreads();
  for (int st = 128; st > 0; st >>= 1) {
    if (tid < st) red[tid] += red[tid + st];
    __syncthreads();
  }
  if (tid == 0) atomicAdd(out, red[0] * (1.f / BATCH));
}

extern "C" void kernel_launch(void* const* d_in, const int* in_sizes, int n_in,
                              void* d_out, int out_size, void* d_ws, size_t ws_size,
                              hipStream_t stream) {
  const float* x = (const float*)d_in[0];
  const float* y = (const float*)d_in[1];
  const void* mask = d_in[2];
  float* out = (float*)d_out;
  char* ws = (char*)d_ws;

  chamfer_items<<<1, 64, 0, stream>>>(mask, ws);
  chamfer_prep<<<2048, 256, 0, stream>>>(x, y, mask, ws, out);
  chamfer_dist<<<512, 512, 0, stream>>>(ws);
  chamfer_reduce<<<128, 256, 0, stream>>>(ws, mask, out);
}